// Round 4
// baseline (309.228 us; speedup 1.0000x reference)
//
#include <hip/hip_runtime.h>
#include <math.h>

// Problem constants (B=1 fixed by reference)
#define NP 9216          // S*S spatial positions
#define DC 256           // channels
#define DN (DC * NP)
#define NT 72            // 9216 / 128 tiles per dim
#define KCH (NP * 32)    // halves per k-chunk section of a plane

#define FEPS 2.220446049250313e-16f

typedef __attribute__((ext_vector_type(8))) _Float16 half8v;
typedef __attribute__((ext_vector_type(4))) float   float4v;

union HU { _Float16 h; unsigned short u; };
__device__ __forceinline__ unsigned short f2h(float f) { HU x; x.h = (_Float16)f; return x.u; }
__device__ __forceinline__ float h2f(unsigned short s) { HU x; x.u = s; return (float)x.h; }

// Plane layout (k-major): half index off(n,k) = (k>>5)*KCH + n*32 + (k&31)
// -> one MFMA fragment load (16 positions x 8 halves) is 1KB contiguous,
// perfectly coalesced global_load_dwordx4. ksim runs with no LDS staging
// and no barriers in the K-loop.
//
// Split (same scale): s' = v*inv*2^8; H = fp16(s'), R = fp16(s' - H).
// sim*2^16 = Hx.Hy + Hx.Ry + Rx.Hy (Rx.Ry dropped, ~2^-22 rel)
// -> three chained MFMAs, no VALU fixup (identical numerics to R2/R3).
//
// R4: Little's-law analysis: R2 delivered 23 B/cyc/CU (vs 60 measured
// ceiling) because each wave's 16 loads are a burst followed by ~900 cyc
// of MFMA with ZERO loads outstanding (avg outstanding ~9KB/CU). R3's
// LDS pipeline was defeated by the __syncthreads vmcnt(0) drain. Fix:
// per-wave REGISTER double-buffer with static ping-pong (no runtime
// indexing -> no scratch): prefetch kt+1's 16 fragments before kt's
// MFMA block. 2 waves/SIMD with continuous 16-load flight is pipe-bound.

// ---------------- Kernel 1: fused normalize + fp16 H/R split ----------------
__global__ __launch_bounds__(256) void kprep(
    const float* __restrict__ X, const float* __restrict__ Y,
    float* __restrict__ Xf_out,
    unsigned short* __restrict__ XH, unsigned short* __restrict__ XR,
    unsigned short* __restrict__ YH, unsigned short* __restrict__ YR,
    float* __restrict__ lacc)
{
    __shared__ float tile[64 * 257];   // (n, d) at n*257+d
    __shared__ float psum[4][64];
    __shared__ float invs[64];

    const int t = threadIdx.x;
    const bool isX = (blockIdx.y == 0);
    const float* src = isX ? X : Y;
    unsigned* hT = (unsigned*)(isX ? XH : YH);
    unsigned* rT = (unsigned*)(isX ? XR : YR);
    const int n0 = blockIdx.x * 64;

    if (blockIdx.x == 0 && blockIdx.y == 0 && t == 0) *lacc = 0.0f;

    const int lane = t & 63;
    const int w    = t >> 6;      // wave id -> owns d-range [w*64, w*64+64)

    #pragma unroll 8
    for (int i = 0; i < 64; ++i) {
        int d = w * 64 + i;
        tile[lane * 257 + d] = src[(size_t)d * NP + n0 + lane];
    }
    float s = 0.0f;
    #pragma unroll 8
    for (int i = 0; i < 64; ++i) {
        float v = tile[lane * 257 + w * 64 + i];
        s = fmaf(v, v, s);
    }
    psum[w][lane] = s;
    __syncthreads();
    if (t < 64) {
        float tot = psum[0][t] + psum[1][t] + psum[2][t] + psum[3][t];
        invs[t] = 1.0f / (sqrtf(tot) + FEPS);
    }
    __syncthreads();

    // plane writes, k-major layout; coalesced uints.
    for (int kt = 0; kt < 8; ++kt) {
        #pragma unroll
        for (int p = 0; p < 4; ++p) {
            int idx = p * 256 + t;
            int n = idx >> 4;          // 0..63
            int u = idx & 15;          // uint within chunk (2 halves)
            float inv = invs[n] * 256.0f;
            int d = kt * 32 + 2 * u;
            float s0 = tile[n * 257 + d] * inv;
            float s1 = tile[n * 257 + d + 1] * inv;
            unsigned short h0 = f2h(s0), h1 = f2h(s1);
            unsigned short r0 = f2h(s0 - h2f(h0));
            unsigned short r1 = f2h(s1 - h2f(h1));
            size_t uo = (size_t)kt * (NP * 16) + (size_t)(n0 + n) * 16 + u;
            hT[uo] = (unsigned)h0 | ((unsigned)h1 << 16);
            rT[uo] = (unsigned)r0 | ((unsigned)r1 << 16);
        }
    }

    // exact fp32 Xf output ([d][n], coalesced over n)
    if (isX) {
        const float inv = invs[lane];
        #pragma unroll 8
        for (int i = 0; i < 64; ++i) {
            int d = w * 64 + i;
            Xf_out[(size_t)d * NP + n0 + lane] = tile[lane * 257 + d] * inv;
        }
    }
}

// ---------------- Kernel 2: reg-pipelined MFMA sim-GEMM + fused argmax ------
// Fragment set for one K=32 step (16 x 1KB coalesced loads / wave).
struct Frags { half8v Ah[4], Ar[4], Bh[4], Br[4]; };

__device__ __forceinline__ void loadf(
    Frags& f,
    const unsigned short* pa, const unsigned short* par,
    const unsigned short* pb, const unsigned short* pbr)
{
    #pragma unroll
    for (int i = 0; i < 4; ++i) {
        f.Ah[i] = *(const half8v*)(pa  + i * 512);
        f.Ar[i] = *(const half8v*)(par + i * 512);
        f.Bh[i] = *(const half8v*)(pb  + i * 512);
        f.Br[i] = *(const half8v*)(pbr + i * 512);
    }
}

__device__ __forceinline__ void mfmaf(const Frags& f, float4v (&acc)[4][4])
{
    #pragma unroll
    for (int cb = 0; cb < 4; ++cb)
        #pragma unroll
        for (int rb = 0; rb < 4; ++rb) {
            float4v v = acc[rb][cb];
            v = __builtin_amdgcn_mfma_f32_16x16x32_f16(f.Ah[rb], f.Bh[cb], v, 0, 0, 0);
            v = __builtin_amdgcn_mfma_f32_16x16x32_f16(f.Ah[rb], f.Br[cb], v, 0, 0, 0);
            v = __builtin_amdgcn_mfma_f32_16x16x32_f16(f.Ar[rb], f.Bh[cb], v, 0, 0, 0);
            acc[rb][cb] = v;
        }
}

__global__ __launch_bounds__(256, 2) void ksim(
    const unsigned short* __restrict__ XH, const unsigned short* __restrict__ XR,
    const unsigned short* __restrict__ YH, const unsigned short* __restrict__ YR,
    float* __restrict__ pmax, int* __restrict__ pidx)
{
    __shared__ float v2s[256];
    __shared__ int   i2s[256];

    const int t = threadIdx.x;

    // ---- XCD-aware block swizzle: lid -> (tx,ty) tile coords ----
    const int lid = blockIdx.y * NT + blockIdx.x;
    const int xcd = lid & 7;
    const int r   = lid >> 3;              // 0..647 within region
    const int sq  = r / 36;                // 6x6 sub-square index (0..17)
    const int wi  = r - sq * 36;           // 0..35 within sub-square
    const int qx  = sq % 3, qy = sq / 3;   // 3x6 grid of sub-squares
    const int sx  = wi % 6,  sy = wi / 6;
    const int tx  = (xcd & 3) * 18 + qx * 6 + sx;   // 0..71
    const int ty  = (xcd >> 2) * 36 + qy * 6 + sy;  // 0..71

    const int n0 = tx * 128;
    const int m0 = ty * 128;

    const int L   = t & 63;
    const int wid = t >> 6;
    const int wnb = (wid >> 1) * 64;   // wave n-offset
    const int wmb = (wid & 1) * 64;    // wave m-offset (col half)
    const int lc  = L & 15;
    const int lq  = L >> 4;

    // fragment base pointers (halves); rb/cb via inst offsets
    const unsigned short* pa  = XH + (size_t)(n0 + wnb + lc) * 32 + lq * 8;
    const unsigned short* par = XR + (size_t)(n0 + wnb + lc) * 32 + lq * 8;
    const unsigned short* pb  = YH + (size_t)(m0 + wmb + lc) * 32 + lq * 8;
    const unsigned short* pbr = YR + (size_t)(m0 + wmb + lc) * 32 + lq * 8;

    float4v acc[4][4];
    #pragma unroll
    for (int i = 0; i < 4; ++i)
        #pragma unroll
        for (int j = 0; j < 4; ++j)
            acc[i][j] = (float4v){0.f, 0.f, 0.f, 0.f};

    // ---- software-pipelined K loop: static ping-pong P/Q register sets.
    // While one set feeds 48 MFMAs, the other set's 16 loads are in flight.
    Frags P, Q;
    loadf(P, pa, par, pb, pbr);

    #pragma unroll 1
    for (int kt = 0; kt < 6; kt += 2) {
        loadf(Q, pa + KCH, par + KCH, pb + KCH, pbr + KCH);
        mfmaf(P, acc);
        pa += 2 * KCH; par += 2 * KCH; pb += 2 * KCH; pbr += 2 * KCH;
        loadf(P, pa, par, pb, pbr);
        mfmaf(Q, acc);
    }
    loadf(Q, pa + KCH, par + KCH, pb + KCH, pbr + KCH);
    mfmaf(P, acc);
    mfmaf(Q, acc);

    // ---- epilogue: per-row argmax over own col-half ----
    // C/D map: col=lane&15, row=lq*4+reg. Scale 2^16 is argmax-invariant.
    float bv[16]; int bc[16];
    #pragma unroll
    for (int s = 0; s < 16; ++s) { bv[s] = -INFINITY; bc[s] = 0; }

    #pragma unroll
    for (int rb = 0; rb < 4; ++rb)
        #pragma unroll
        for (int cb = 0; cb < 4; ++cb) {   // cb ascending = col ascending
            const int col = m0 + wmb + cb * 16 + lc;
            #pragma unroll
            for (int r2 = 0; r2 < 4; ++r2) {
                float v = acc[rb][cb][r2];
                int s = rb * 4 + r2;
                if (v > bv[s]) { bv[s] = v; bc[s] = col; }
            }
        }

    // reduce across the 16 lc lanes (xor<16 stays in the quad-group)
    #pragma unroll
    for (int off = 1; off < 16; off <<= 1) {
        #pragma unroll
        for (int s = 0; s < 16; ++s) {
            float ov = __shfl_xor(bv[s], off, 64);
            int   oi = __shfl_xor(bc[s], off, 64);
            if (ov > bv[s] || (ov == bv[s] && oi < bc[s])) { bv[s] = ov; bc[s] = oi; }
        }
    }

    // combine the two column-halves via LDS -> one slot per tile.
    // half0 cols < half1 cols: strict '>' keeps half0 on ties (first-max).
    if (lc == 0) {
        const int half = wid & 1;
        #pragma unroll
        for (int rb = 0; rb < 4; ++rb)
            #pragma unroll
            for (int r2 = 0; r2 < 4; ++r2) {
                int rl = wnb + rb * 16 + lq * 4 + r2;
                v2s[half * 128 + rl] = bv[rb * 4 + r2];
                i2s[half * 128 + rl] = bc[rb * 4 + r2];
            }
    }
    __syncthreads();
    if (t < 128) {
        float va = v2s[t], vb = v2s[128 + t];
        int   ia = i2s[t], ib = i2s[128 + t];
        bool useB = vb > va;
        pmax[(size_t)ty * NP + n0 + t] = useB ? vb : va;
        pidx[(size_t)ty * NP + n0 + t] = useB ? ib : ia;
    }
}

// ---------------- Kernel 3: reduce 72 tile partials -> nn_idx -------------
__global__ __launch_bounds__(256) void kred(
    const float* __restrict__ pmax, const int* __restrict__ pidx,
    int* __restrict__ nn)
{
    __shared__ float cv[4][64];
    __shared__ int   ci[4][64];

    const int t = threadIdx.x;
    const int n = blockIdx.x * 64 + (t & 63);
    const int p = t >> 6;

    float b = -INFINITY;
    int bi = 0x7fffffff;
    #pragma unroll 6
    for (int c = p * 18; c < p * 18 + 18; ++c) {
        float v = pmax[(size_t)c * NP + n];
        int  id = pidx[(size_t)c * NP + n];
        if (v > b || (v == b && id < bi)) { b = v; bi = id; }
    }
    cv[p][t & 63] = b;
    ci[p][t & 63] = bi;
    __syncthreads();
    if (t < 64) {
        b = cv[0][t]; bi = ci[0][t];
        #pragma unroll
        for (int q = 1; q < 4; ++q) {
            float v = cv[q][t]; int id = ci[q][t];
            if (v > b || (v == b && id < bi)) { b = v; bi = id; }
        }
        nn[blockIdx.x * 64 + t] = bi;
    }
}

// ---------------- Kernel 4: gather Y_sel + fused MSE loss ----------------
// y = (H + R) * 2^-8 (H/R same scale; error ~2^-22 relative).
__global__ __launch_bounds__(256) void kgather(
    const unsigned short* __restrict__ YH, const unsigned short* __restrict__ YR,
    const int* __restrict__ nn,
    const float* __restrict__ Xf, float* __restrict__ Ysel,
    float* __restrict__ lacc)
{
    __shared__ float tile[64][65];
    __shared__ int   idxs[64];
    __shared__ float wsum[4];

    const int n0 = blockIdx.x * 64;
    const int d0 = blockIdx.y * 64;
    const int tid = threadIdx.x;

    if (tid < 64) idxs[tid] = nn[n0 + tid];
    __syncthreads();

    const int c  = tid & 63;
    const int r0 = tid >> 6;

    #pragma unroll
    for (int s = 0; s < 16; ++s) {
        int r = s * 4 + r0;
        int d = d0 + c;
        size_t off = (size_t)(d >> 5) * KCH + (size_t)idxs[r] * 32 + (d & 31);
        tile[r][c] = (h2f(YH[off]) + h2f(YR[off])) * (1.0f / 256.0f);
    }
    __syncthreads();

    float lsum = 0.0f;
    #pragma unroll
    for (int s = 0; s < 16; ++s) {
        int a = s * 4 + r0;
        int d = d0 + a;
        int n = n0 + c;
        float y = tile[c][a];          // stride-65: conflict-free
        float x = Xf[(size_t)d * NP + n];
        float diff = x - y;
        lsum = fmaf(diff, diff, lsum);
        Ysel[(size_t)d * NP + n] = y;  // coalesced over n
    }

    #pragma unroll
    for (int off = 32; off >= 1; off >>= 1)
        lsum += __shfl_xor(lsum, off, 64);
    if ((tid & 63) == 0) wsum[tid >> 6] = lsum;
    __syncthreads();
    if (tid == 0)
        atomicAdd(lacc, wsum[0] + wsum[1] + wsum[2] + wsum[3]);
}

// ---------------- Kernel 5: finalize loss ----------------
__global__ void kfin(const float* __restrict__ lacc, float* __restrict__ out)
{
    out[0] = lacc[0] * (1.0f / (float)DN);
}

extern "C" void kernel_launch(void* const* d_in, const int* in_sizes, int n_in,
                              void* d_out, int out_size, void* d_ws, size_t ws_size,
                              hipStream_t stream)
{
    const float* X = (const float*)d_in[0];   // X_features [1,256,96,96]
    const float* Y = (const float*)d_in[1];   // Y_features [1,256,96,96]
    // d_in[2], d_in[3] (images) are dead code in the reference — unused.

    float* out = (float*)d_out;
    float* Ysel_out = out + 1;          // output 1: Y_sel [1,D,N]
    float* Xf_out   = out + 1 + DN;     // output 2: Xf   [1,D,N]  (exact fp32)

    // Workspace (~24.3 MB)
    unsigned short* XH = (unsigned short*)d_ws;   // DN halves each
    unsigned short* XR = XH + DN;
    unsigned short* YH = XR + DN;
    unsigned short* YR = YH + DN;
    float* pmax = (float*)(YR + DN);                // NT*NP
    int*   pidx = (int*)(pmax + (size_t)NT * NP);   // NT*NP
    int*   nn   = pidx + (size_t)NT * NP;           // NP
    float* lacc = (float*)(nn + NP);                // 1

    hipLaunchKernelGGL(kprep, dim3(NP / 64, 2), dim3(256), 0, stream,
                       X, Y, Xf_out, XH, XR, YH, YR, lacc);
    hipLaunchKernelGGL(ksim, dim3(NT, NT), dim3(256), 0, stream,
                       XH, XR, YH, YR, pmax, pidx);
    hipLaunchKernelGGL(kred, dim3(NP / 64), dim3(256), 0, stream,
                       pmax, pidx, nn);
    hipLaunchKernelGGL(kgather, dim3(NP / 64, DC / 64), dim3(256), 0, stream,
                       YH, YR, nn, Xf_out, Ysel_out, lacc);
    hipLaunchKernelGGL(kfin, dim3(1), dim3(1), 0, stream, lacc, out);
}

// Round 5
// 258.998 us; speedup vs baseline: 1.1939x; 1.1939x over previous
//
#include <hip/hip_runtime.h>
#include <math.h>

// Problem constants (B=1 fixed by reference)
#define NP 9216          // S*S spatial positions
#define DC 256           // channels
#define DN (DC * NP)
#define NCH 24           // 9216 / 384 column chunks
#define NST 72           // 9216 / 128 row stripes
#define KCH (NP * 32)    // halves per k-chunk section of a plane

#define FEPS 2.220446049250313e-16f

typedef __attribute__((ext_vector_type(8))) _Float16 half8v;
typedef __attribute__((ext_vector_type(4))) float   float4v;

union HU { _Float16 h; unsigned short u; };
__device__ __forceinline__ unsigned short f2h(float f) { HU x; x.h = (_Float16)f; return x.u; }
__device__ __forceinline__ float h2f(unsigned short s) { HU x; x.u = s; return (float)x.h; }

// Plane layout (k-major): half index off(n,k) = (k>>5)*KCH + n*32 + (k&31)
// Split (same scale): s' = v*inv*2^8; H = fp16(s'), R = fp16(s' - H).
// sim*2^16 = Hx.Hy + Hx.Ry + Rx.Hy (Rx.Ry dropped, ~2^-22 rel).
//
// R5 model (from R0-R4 counters): ksim is ISSUED-BYTE-bound at ~23 B/cyc/CU
// (14.4 TB/s) L2->CU delivery; latency blowup is queueing at that wall.
// Fix: A stripe (128 rows, full K, both planes = 128 KB) persistent in LDS,
// staged ONCE per block; 12 waves stream B fragment-direct with ZERO
// barriers in the K-loop (R2's proven schedule). Issued: 2.65 -> 1.56 GB.

// ---------------- Kernel 1: fused normalize + fp16 H/R split ----------------
__global__ __launch_bounds__(256) void kprep(
    const float* __restrict__ X, const float* __restrict__ Y,
    float* __restrict__ Xf_out,
    unsigned short* __restrict__ XH, unsigned short* __restrict__ XR,
    unsigned short* __restrict__ YH, unsigned short* __restrict__ YR,
    float* __restrict__ lacc)
{
    __shared__ float tile[64 * 257];   // (n, d) at n*257+d
    __shared__ float psum[4][64];
    __shared__ float invs[64];

    const int t = threadIdx.x;
    const bool isX = (blockIdx.y == 0);
    const float* src = isX ? X : Y;
    unsigned* hT = (unsigned*)(isX ? XH : YH);
    unsigned* rT = (unsigned*)(isX ? XR : YR);
    const int n0 = blockIdx.x * 64;

    if (blockIdx.x == 0 && blockIdx.y == 0 && t == 0) *lacc = 0.0f;

    const int lane = t & 63;
    const int w    = t >> 6;      // wave id -> owns d-range [w*64, w*64+64)

    #pragma unroll 8
    for (int i = 0; i < 64; ++i) {
        int d = w * 64 + i;
        tile[lane * 257 + d] = src[(size_t)d * NP + n0 + lane];
    }
    float s = 0.0f;
    #pragma unroll 8
    for (int i = 0; i < 64; ++i) {
        float v = tile[lane * 257 + w * 64 + i];
        s = fmaf(v, v, s);
    }
    psum[w][lane] = s;
    __syncthreads();
    if (t < 64) {
        float tot = psum[0][t] + psum[1][t] + psum[2][t] + psum[3][t];
        invs[t] = 1.0f / (sqrtf(tot) + FEPS);
    }
    __syncthreads();

    // plane writes, k-major layout; coalesced uints.
    for (int kt = 0; kt < 8; ++kt) {
        #pragma unroll
        for (int p = 0; p < 4; ++p) {
            int idx = p * 256 + t;
            int n = idx >> 4;          // 0..63
            int u = idx & 15;          // uint within chunk (2 halves)
            float inv = invs[n] * 256.0f;
            int d = kt * 32 + 2 * u;
            float s0 = tile[n * 257 + d] * inv;
            float s1 = tile[n * 257 + d + 1] * inv;
            unsigned short h0 = f2h(s0), h1 = f2h(s1);
            unsigned short r0 = f2h(s0 - h2f(h0));
            unsigned short r1 = f2h(s1 - h2f(h1));
            size_t uo = (size_t)kt * (NP * 16) + (size_t)(n0 + n) * 16 + u;
            hT[uo] = (unsigned)h0 | ((unsigned)h1 << 16);
            rT[uo] = (unsigned)r0 | ((unsigned)r1 << 16);
        }
    }

    // exact fp32 Xf output ([d][n], coalesced over n)
    if (isX) {
        const float inv = invs[lane];
        #pragma unroll 8
        for (int i = 0; i < 64; ++i) {
            int d = w * 64 + i;
            Xf_out[(size_t)d * NP + n0 + lane] = tile[lane * 257 + d] * inv;
        }
    }
}

// ---------------- Kernel 2: A-LDS stripe + barrier-free B-stream GEMM -------
__device__ __forceinline__ void glds16(const char* g, char* l)
{
    __builtin_amdgcn_global_load_lds(
        (const __attribute__((address_space(1))) void*)g,
        (__attribute__((address_space(3))) void*)l, 16, 0, 0);
}

__device__ __forceinline__ void mfma3(
    const half8v (&Ah)[4], const half8v (&Ar)[4],
    const half8v (&Bh)[4], const half8v (&Br)[4], float4v (&acc)[4][4])
{
    #pragma unroll
    for (int cb = 0; cb < 4; ++cb)
        #pragma unroll
        for (int rb = 0; rb < 4; ++rb) {
            float4v v = acc[rb][cb];
            v = __builtin_amdgcn_mfma_f32_16x16x32_f16(Ah[rb], Bh[cb], v, 0, 0, 0);
            v = __builtin_amdgcn_mfma_f32_16x16x32_f16(Ah[rb], Br[cb], v, 0, 0, 0);
            v = __builtin_amdgcn_mfma_f32_16x16x32_f16(Ar[rb], Bh[cb], v, 0, 0, 0);
            acc[rb][cb] = v;
        }
}

__global__ __launch_bounds__(768, 3) void ksim(
    const unsigned short* __restrict__ XH,
    const unsigned short* __restrict__ YH, const unsigned short* __restrict__ YR,
    float* __restrict__ pmax, int* __restrict__ pidx)
{
    extern __shared__ char smem[];     // 128 KB A (swizzled) + 6 KB tables

    const int t = threadIdx.x;

    // ---- XCD swizzle: each XCD owns 3 column-chunks x all stripes; the 3
    // blocks sharing a stripe are consecutive -> A slice stays L2-hot.
    const int lid = blockIdx.y * NCH + blockIdx.x;
    const int xcd = lid & 7;
    const int r   = lid >> 3;            // 0..215
    const int tx  = xcd * 3 + r % 3;     // chunk 0..23
    const int ty  = r / 3;               // stripe 0..71
    const int n0  = ty * 128;
    const int m0  = tx * 384;

    const int L = t & 63, wid = t >> 6;
    const int wm = wid / 6, wn = wid - wm * 6;   // 2M x 6N wave grid
    const int lc = L & 15,  lq = L >> 4;

    // ---- B fragment pointers (stream from global, R2 pattern) ----
    const unsigned short* pb  = YH + (size_t)(m0 + wn * 64 + lc) * 32 + lq * 8;
    const unsigned short* pbr = YR + (size_t)(m0 + wn * 64 + lc) * 32 + lq * 8;

    // kt0 B loads issued FIRST (vmem retires in order: these complete before
    // the staging insts below, so the compiler's wait for them is cheap).
    half8v Bh[4], Br[4];
    #pragma unroll
    for (int i = 0; i < 4; ++i) {
        Bh[i] = *(const half8v*)(pb  + i * 512);
        Br[i] = *(const half8v*)(pbr + i * 512);
    }
    asm volatile("" ::: "memory");

    // ---- stage A stripe: 8192 segs of 16 B; seg = kt*1024 + pl*512 + s.
    // LDS linear dest; source inverse-XOR-swizzled (rule 21) so that the
    // swizzled ds_read below is conflict-reduced.
    {
        const char* Ab = (const char*)XH + (size_t)n0 * 64;
        #pragma unroll
        for (int i = 0; i < 11; ++i) {
            if (i < 10 || t < 512) {               // wave-uniform guard
                const int seg = i * 768 + t;
                const int kt  = seg >> 10;
                const int pl  = (seg >> 9) & 1;
                const int d   = (seg & 511) << 4;  // byte off in 8 KB chunk
                const int sw  = ((d >> 6) & 3) << 4;
                const char* src = Ab + (size_t)pl * (2 * (size_t)DN)
                                + (size_t)kt * (2 * (size_t)KCH) + (d ^ sw);
                glds16(src, smem + (size_t)seg * 16);
            }
        }
    }
    // kt0 segs are each wave's oldest <=2 staging insts -> vmcnt(9) + barrier
    // makes kt0 globally ready without draining the rest.
    asm volatile("s_waitcnt vmcnt(9)" ::: "memory");
    __builtin_amdgcn_s_barrier();
    asm volatile("" ::: "memory");

    float4v acc[4][4];
    #pragma unroll
    for (int i = 0; i < 4; ++i)
        #pragma unroll
        for (int j = 0; j < 4; ++j)
            acc[i][j] = (float4v){0.f, 0.f, 0.f, 0.f};

    // swizzled A read offset: row = wm*64 + rb*16 + lc  (row&3 == lc&3)
    const int arow = (wm * 64 + lc) * 64 + ((lq * 16) ^ ((lc & 3) << 4));
    const char* sA = smem;

    // ---- kt0 (A from LDS, B preloaded) ----
    {
        half8v Ah[4], Ar[4];
        #pragma unroll
        for (int i = 0; i < 4; ++i) {
            Ah[i] = *(const half8v*)(sA +        arow + i * 1024);
            Ar[i] = *(const half8v*)(sA + 8192 + arow + i * 1024);
        }
        mfma3(Ah, Ar, Bh, Br, acc);
        pb += KCH; pbr += KCH;
    }
    __syncthreads();        // full drain: entire A stripe landed
    sA += 16384;

    // ---- kt 1..7: barrier-free ----
    #pragma unroll 1
    for (int kt = 1; kt < 8; ++kt) {
        #pragma unroll
        for (int i = 0; i < 4; ++i) {
            Bh[i] = *(const half8v*)(pb  + i * 512);
            Br[i] = *(const half8v*)(pbr + i * 512);
        }
        half8v Ah[4], Ar[4];
        #pragma unroll
        for (int i = 0; i < 4; ++i) {
            Ah[i] = *(const half8v*)(sA +        arow + i * 1024);
            Ar[i] = *(const half8v*)(sA + 8192 + arow + i * 1024);
        }
        mfma3(Ah, Ar, Bh, Br, acc);
        pb += KCH; pbr += KCH; sA += 16384;
    }

    // ---- epilogue: per-row argmax over this wave's 64 cols ----
    // C/D map: col=lane&15, row=lq*4+reg. Scale 2^16 is argmax-invariant.
    float bv[16]; int bc[16];
    #pragma unroll
    for (int s = 0; s < 16; ++s) { bv[s] = -INFINITY; bc[s] = 0; }

    #pragma unroll
    for (int rb = 0; rb < 4; ++rb)
        #pragma unroll
        for (int cb = 0; cb < 4; ++cb) {   // cb ascending = col ascending
            const int col = m0 + wn * 64 + cb * 16 + lc;
            #pragma unroll
            for (int r2 = 0; r2 < 4; ++r2) {
                float v = acc[rb][cb][r2];
                int s = rb * 4 + r2;
                if (v > bv[s]) { bv[s] = v; bc[s] = col; }
            }
        }

    // reduce across the 16 lc lanes (xor<16 stays in the quad-group)
    #pragma unroll
    for (int off = 1; off < 16; off <<= 1) {
        #pragma unroll
        for (int s = 0; s < 16; ++s) {
            float ov = __shfl_xor(bv[s], off, 64);
            int   oi = __shfl_xor(bc[s], off, 64);
            if (ov > bv[s] || (ov == bv[s] && oi < bc[s])) { bv[s] = ov; bc[s] = oi; }
        }
    }

    // combine 6 column-chunk waves per row via LDS table [128][6].
    // wn ascending = col ascending: strict '>' keeps first-max semantics.
    float* v2s = (float*)(smem + 131072);
    int*   i2s = (int*)(smem + 131072 + 3072);

    if (lc == 0) {
        #pragma unroll
        for (int rb = 0; rb < 4; ++rb)
            #pragma unroll
            for (int r2 = 0; r2 < 4; ++r2) {
                int row = wm * 64 + rb * 16 + lq * 4 + r2;
                v2s[row * 6 + wn] = bv[rb * 4 + r2];
                i2s[row * 6 + wn] = bc[rb * 4 + r2];
            }
    }
    __syncthreads();
    if (t < 128) {
        float b = v2s[t * 6]; int bi = i2s[t * 6];
        #pragma unroll
        for (int q = 1; q < 6; ++q) {
            float v = v2s[t * 6 + q];
            if (v > b) { b = v; bi = i2s[t * 6 + q]; }
        }
        pmax[(size_t)tx * NP + n0 + t] = b;
        pidx[(size_t)tx * NP + n0 + t] = bi;
    }
}

// ---------------- Kernel 3: reduce 24 chunk partials -> nn_idx -------------
__global__ __launch_bounds__(256) void kred(
    const float* __restrict__ pmax, const int* __restrict__ pidx,
    int* __restrict__ nn)
{
    __shared__ float cv[4][64];
    __shared__ int   ci[4][64];

    const int t = threadIdx.x;
    const int n = blockIdx.x * 64 + (t & 63);
    const int p = t >> 6;

    float b = -INFINITY;
    int bi = 0x7fffffff;
    #pragma unroll
    for (int c = p * 6; c < p * 6 + 6; ++c) {
        float v = pmax[(size_t)c * NP + n];
        int  id = pidx[(size_t)c * NP + n];
        if (v > b || (v == b && id < bi)) { b = v; bi = id; }
    }
    cv[p][t & 63] = b;
    ci[p][t & 63] = bi;
    __syncthreads();
    if (t < 64) {
        b = cv[0][t]; bi = ci[0][t];
        #pragma unroll
        for (int q = 1; q < 4; ++q) {
            float v = cv[q][t]; int id = ci[q][t];
            if (v > b || (v == b && id < bi)) { b = v; bi = id; }
        }
        nn[blockIdx.x * 64 + t] = bi;
    }
}

// ---------------- Kernel 4: gather Y_sel + fused MSE loss ----------------
// y = (H + R) * 2^-8 (H/R same scale; error ~2^-22 relative).
__global__ __launch_bounds__(256) void kgather(
    const unsigned short* __restrict__ YH, const unsigned short* __restrict__ YR,
    const int* __restrict__ nn,
    const float* __restrict__ Xf, float* __restrict__ Ysel,
    float* __restrict__ lacc)
{
    __shared__ float tile[64][65];
    __shared__ int   idxs[64];
    __shared__ float wsum[4];

    const int n0 = blockIdx.x * 64;
    const int d0 = blockIdx.y * 64;
    const int tid = threadIdx.x;

    if (tid < 64) idxs[tid] = nn[n0 + tid];
    __syncthreads();

    const int c  = tid & 63;
    const int r0 = tid >> 6;

    #pragma unroll
    for (int s = 0; s < 16; ++s) {
        int r = s * 4 + r0;
        int d = d0 + c;
        size_t off = (size_t)(d >> 5) * KCH + (size_t)idxs[r] * 32 + (d & 31);
        tile[r][c] = (h2f(YH[off]) + h2f(YR[off])) * (1.0f / 256.0f);
    }
    __syncthreads();

    float lsum = 0.0f;
    #pragma unroll
    for (int s = 0; s < 16; ++s) {
        int a = s * 4 + r0;
        int d = d0 + a;
        int n = n0 + c;
        float y = tile[c][a];          // stride-65: conflict-free
        float x = Xf[(size_t)d * NP + n];
        float diff = x - y;
        lsum = fmaf(diff, diff, lsum);
        Ysel[(size_t)d * NP + n] = y;  // coalesced over n
    }

    #pragma unroll
    for (int off = 32; off >= 1; off >>= 1)
        lsum += __shfl_xor(lsum, off, 64);
    if ((tid & 63) == 0) wsum[tid >> 6] = lsum;
    __syncthreads();
    if (tid == 0)
        atomicAdd(lacc, wsum[0] + wsum[1] + wsum[2] + wsum[3]);
}

// ---------------- Kernel 5: finalize loss ----------------
__global__ void kfin(const float* __restrict__ lacc, float* __restrict__ out)
{
    out[0] = lacc[0] * (1.0f / (float)DN);
}

extern "C" void kernel_launch(void* const* d_in, const int* in_sizes, int n_in,
                              void* d_out, int out_size, void* d_ws, size_t ws_size,
                              hipStream_t stream)
{
    const float* X = (const float*)d_in[0];   // X_features [1,256,96,96]
    const float* Y = (const float*)d_in[1];   // Y_features [1,256,96,96]
    // d_in[2], d_in[3] (images) are dead code in the reference — unused.

    float* out = (float*)d_out;
    float* Ysel_out = out + 1;          // output 1: Y_sel [1,D,N]
    float* Xf_out   = out + 1 + DN;     // output 2: Xf   [1,D,N]  (exact fp32)

    // Workspace (~20 MB). XH|XR MUST be contiguous (ksim derives XR = XH+DN).
    unsigned short* XH = (unsigned short*)d_ws;   // DN halves each
    unsigned short* XR = XH + DN;
    unsigned short* YH = XR + DN;
    unsigned short* YR = YH + DN;
    float* pmax = (float*)(YR + DN);                 // NCH*NP
    int*   pidx = (int*)(pmax + (size_t)NCH * NP);   // NCH*NP
    int*   nn   = pidx + (size_t)NCH * NP;           // NP
    float* lacc = (float*)(nn + NP);                 // 1

    static bool attr_done = false;
    if (!attr_done) {
        hipFuncSetAttribute(reinterpret_cast<const void*>(ksim),
                            hipFuncAttributeMaxDynamicSharedMemorySize, 137216);
        attr_done = true;
    }

    hipLaunchKernelGGL(kprep, dim3(NP / 64, 2), dim3(256), 0, stream,
                       X, Y, Xf_out, XH, XR, YH, YR, lacc);
    hipLaunchKernelGGL(ksim, dim3(NCH, NST), dim3(768), 137216, stream,
                       XH, YH, YR, pmax, pidx);
    hipLaunchKernelGGL(kred, dim3(NP / 64), dim3(256), 0, stream,
                       pmax, pidx, nn);
    hipLaunchKernelGGL(kgather, dim3(NP / 64, DC / 64), dim3(256), 0, stream,
                       YH, YR, nn, Xf_out, Ysel_out, lacc);
    hipLaunchKernelGGL(kfin, dim3(1), dim3(1), 0, stream, lacc, out);
}

// Round 6
// 250.831 us; speedup vs baseline: 1.2328x; 1.0326x over previous
//
#include <hip/hip_runtime.h>
#include <math.h>

// Problem constants (B=1 fixed by reference)
#define NP 9216          // S*S spatial positions
#define DC 256           // channels
#define DN (DC * NP)
#define NCH 24           // 9216 / 384 column chunks
#define NST 72           // 9216 / 128 row stripes
#define KCH (NP * 32)    // halves per k-chunk section of a plane

#define FEPS 2.220446049250313e-16f

typedef __attribute__((ext_vector_type(8))) _Float16 half8v;
typedef __attribute__((ext_vector_type(4))) float   float4v;

union HU { _Float16 h; unsigned short u; };
__device__ __forceinline__ unsigned short f2h(float f) { HU x; x.h = (_Float16)f; return x.u; }
__device__ __forceinline__ float h2f(unsigned short s) { HU x; x.u = s; return (float)x.h; }

// Plane layout (k-major): half index off(n,k) = (k>>5)*KCH + n*32 + (k&31)
// Split (same scale): s' = v*inv*2^8; H = fp16(s'), R = fp16(s' - H).
// sim*2^16 = Hx.Hy + Hx.Ry + Rx.Hy (Rx.Ry dropped, ~2^-22 rel).
//
// R6 model: R5 left the byte-wall (15.4 B/cyc/CU < 23 wall) but MfmaUtil
// stuck at 34% = per-kt B-load latency fully exposed (loads issued right
// before their MFMAs; 3 waves/SIMD convoy together). Fixes:
//  (1) B-only register prefetch (BE/BO static ping-pong, +32 VGPR) with
//      rb-outer MFMA loop (A transient 8 VGPR) -> ~150 VGPR, still 3
//      waves/SIMD: R4's prefetch win WITHOUT R4's occupancy loss.
//  (2) LDS swizzle bits (row>>1)&3 (R5's row&3 aliased with the row&1
//      bank bit -> 4-way conflict, 5.37M cycles measured).

// ---------------- Kernel 1: fused normalize + fp16 H/R split ----------------
__global__ __launch_bounds__(256) void kprep(
    const float* __restrict__ X, const float* __restrict__ Y,
    float* __restrict__ Xf_out,
    unsigned short* __restrict__ XH, unsigned short* __restrict__ XR,
    unsigned short* __restrict__ YH, unsigned short* __restrict__ YR,
    float* __restrict__ lacc)
{
    __shared__ float tile[64 * 257];   // (n, d) at n*257+d
    __shared__ float psum[4][64];
    __shared__ float invs[64];

    const int t = threadIdx.x;
    const bool isX = (blockIdx.y == 0);
    const float* src = isX ? X : Y;
    unsigned* hT = (unsigned*)(isX ? XH : YH);
    unsigned* rT = (unsigned*)(isX ? XR : YR);
    const int n0 = blockIdx.x * 64;

    if (blockIdx.x == 0 && blockIdx.y == 0 && t == 0) *lacc = 0.0f;

    const int lane = t & 63;
    const int w    = t >> 6;      // wave id -> owns d-range [w*64, w*64+64)

    #pragma unroll 8
    for (int i = 0; i < 64; ++i) {
        int d = w * 64 + i;
        tile[lane * 257 + d] = src[(size_t)d * NP + n0 + lane];
    }
    float s = 0.0f;
    #pragma unroll 8
    for (int i = 0; i < 64; ++i) {
        float v = tile[lane * 257 + w * 64 + i];
        s = fmaf(v, v, s);
    }
    psum[w][lane] = s;
    __syncthreads();
    if (t < 64) {
        float tot = psum[0][t] + psum[1][t] + psum[2][t] + psum[3][t];
        invs[t] = 1.0f / (sqrtf(tot) + FEPS);
    }
    __syncthreads();

    // plane writes, k-major layout; coalesced uints.
    for (int kt = 0; kt < 8; ++kt) {
        #pragma unroll
        for (int p = 0; p < 4; ++p) {
            int idx = p * 256 + t;
            int n = idx >> 4;          // 0..63
            int u = idx & 15;          // uint within chunk (2 halves)
            float inv = invs[n] * 256.0f;
            int d = kt * 32 + 2 * u;
            float s0 = tile[n * 257 + d] * inv;
            float s1 = tile[n * 257 + d + 1] * inv;
            unsigned short h0 = f2h(s0), h1 = f2h(s1);
            unsigned short r0 = f2h(s0 - h2f(h0));
            unsigned short r1 = f2h(s1 - h2f(h1));
            size_t uo = (size_t)kt * (NP * 16) + (size_t)(n0 + n) * 16 + u;
            hT[uo] = (unsigned)h0 | ((unsigned)h1 << 16);
            rT[uo] = (unsigned)r0 | ((unsigned)r1 << 16);
        }
    }

    // exact fp32 Xf output ([d][n], coalesced over n)
    if (isX) {
        const float inv = invs[lane];
        #pragma unroll 8
        for (int i = 0; i < 64; ++i) {
            int d = w * 64 + i;
            Xf_out[(size_t)d * NP + n0 + lane] = tile[lane * 257 + d] * inv;
        }
    }
}

// ---------------- Kernel 2: A-LDS stripe + B-prefetch streamed GEMM ---------
__device__ __forceinline__ void glds16(const char* g, char* l)
{
    __builtin_amdgcn_global_load_lds(
        (const __attribute__((address_space(1))) void*)g,
        (__attribute__((address_space(3))) void*)l, 16, 0, 0);
}

// rb-outer MFMA sweep: A fragments read pairwise from LDS (8 VGPR live)
__device__ __forceinline__ void mfma_sweep(
    const char* sA, int arow,
    const half8v (&Bh)[4], const half8v (&Br)[4], float4v (&acc)[4][4])
{
    #pragma unroll
    for (int rb = 0; rb < 4; ++rb) {
        half8v Ah = *(const half8v*)(sA +        arow + rb * 1024);
        half8v Ar = *(const half8v*)(sA + 8192 + arow + rb * 1024);
        #pragma unroll
        for (int cb = 0; cb < 4; ++cb) {
            float4v v = acc[rb][cb];
            v = __builtin_amdgcn_mfma_f32_16x16x32_f16(Ah, Bh[cb], v, 0, 0, 0);
            v = __builtin_amdgcn_mfma_f32_16x16x32_f16(Ah, Br[cb], v, 0, 0, 0);
            v = __builtin_amdgcn_mfma_f32_16x16x32_f16(Ar, Bh[cb], v, 0, 0, 0);
            acc[rb][cb] = v;
        }
    }
}

#define LOADB(dsth, dstr)                                   \
    {                                                       \
        _Pragma("unroll")                                   \
        for (int i = 0; i < 4; ++i) {                       \
            dsth[i] = *(const half8v*)(pb  + i * 512);      \
            dstr[i] = *(const half8v*)(pbr + i * 512);      \
        }                                                   \
        pb += KCH; pbr += KCH;                              \
    }

__global__ __launch_bounds__(768, 3) void ksim(
    const unsigned short* __restrict__ XH,
    const unsigned short* __restrict__ YH, const unsigned short* __restrict__ YR,
    float* __restrict__ pmax, int* __restrict__ pidx)
{
    extern __shared__ char smem[];     // 128 KB A (swizzled) + 6 KB tables

    const int t = threadIdx.x;

    // ---- XCD swizzle: each XCD owns 3 column-chunks x all stripes; the 3
    // blocks sharing a stripe are consecutive -> A slice stays L2-hot.
    const int lid = blockIdx.y * NCH + blockIdx.x;
    const int xcd = lid & 7;
    const int r   = lid >> 3;            // 0..215
    const int tx  = xcd * 3 + r % 3;     // chunk 0..23
    const int ty  = r / 3;               // stripe 0..71
    const int n0  = ty * 128;
    const int m0  = tx * 384;

    const int L = t & 63, wid = t >> 6;
    const int wm = wid / 6, wn = wid - wm * 6;   // 2M x 6N wave grid
    const int lc = L & 15,  lq = L >> 4;

    // ---- B fragment pointers (stream from global) ----
    const unsigned short* pb  = YH + (size_t)(m0 + wn * 64 + lc) * 32 + lq * 8;
    const unsigned short* pbr = YR + (size_t)(m0 + wn * 64 + lc) * 32 + lq * 8;

    // kt0 B loads issued FIRST (oldest vmem -> drained cheaply later).
    half8v BEh[4], BEr[4], BOh[4], BOr[4];
    LOADB(BEh, BEr);                    // kt0
    asm volatile("" ::: "memory");

    // ---- stage A stripe: 8192 segs of 16 B; seg = kt*1024 + pl*512 + s.
    // LDS linear dest; source inverse-XOR-swizzled with (row>>1)&3 (bits
    // independent of the row&1 bank bit -> all 32 banks covered on read).
    {
        const char* Ab = (const char*)XH + (size_t)n0 * 64;
        #pragma unroll
        for (int i = 0; i < 11; ++i) {
            if (i < 10 || t < 512) {               // wave-uniform guard
                const int seg = i * 768 + t;
                const int kt  = seg >> 10;
                const int pl  = (seg >> 9) & 1;
                const int d   = (seg & 511) << 4;  // byte off in 8 KB chunk
                const int sw  = ((d >> 7) & 3) << 4;
                const char* src = Ab + (size_t)pl * (2 * (size_t)DN)
                                + (size_t)kt * (2 * (size_t)KCH) + (d ^ sw);
                glds16(src, smem + (size_t)seg * 16);
            }
        }
    }
    // kt0 A segs are each thread's oldest staging ops: vmcnt(9) makes kt0
    // ready without draining the rest of the stripe.
    asm volatile("s_waitcnt vmcnt(9)" ::: "memory");
    __builtin_amdgcn_s_barrier();
    asm volatile("" ::: "memory");

    float4v acc[4][4];
    #pragma unroll
    for (int i = 0; i < 4; ++i)
        #pragma unroll
        for (int j = 0; j < 4; ++j)
            acc[i][j] = (float4v){0.f, 0.f, 0.f, 0.f};

    // swizzled A read offset: row = wm*64 + rb*16 + lc; (row>>1)&3 == (lc>>1)&3
    const int arow = (wm * 64 + lc) * 64 + ((lq * 16) ^ (((lc >> 1) & 3) << 4));

    // ---- kt0: prefetch kt1 B, compute kt0 from preloaded BE ----
    LOADB(BOh, BOr);                    // kt1 in flight across kt0 compute
    mfma_sweep(smem, arow, BEh, BEr, acc);

    // Counted drain: BO's 8 loads are the 8 newest vmem ops -> vmcnt(8)
    // completes ALL A staging while keeping the kt1 prefetch in flight.
    asm volatile("s_waitcnt vmcnt(8)" ::: "memory");
    __builtin_amdgcn_s_barrier();
    asm volatile("" ::: "memory");

    // ---- kt 1..7: barrier-free, one-tile-ahead B prefetch ----
    #pragma unroll 1
    for (int kt = 1; kt < 7; kt += 2) {
        LOADB(BEh, BEr);                                    // kt+1
        mfma_sweep(smem + kt * 16384, arow, BOh, BOr, acc); // kt (odd)
        LOADB(BOh, BOr);                                    // kt+2
        mfma_sweep(smem + (kt + 1) * 16384, arow, BEh, BEr, acc); // kt+1
    }
    mfma_sweep(smem + 7 * 16384, arow, BOh, BOr, acc);      // kt7

    // ---- epilogue: per-row argmax over this wave's 64 cols ----
    // C/D map: col=lane&15, row=lq*4+reg. Scale 2^16 is argmax-invariant.
    float bv[16]; int bc[16];
    #pragma unroll
    for (int s = 0; s < 16; ++s) { bv[s] = -INFINITY; bc[s] = 0; }

    #pragma unroll
    for (int rb = 0; rb < 4; ++rb)
        #pragma unroll
        for (int cb = 0; cb < 4; ++cb) {   // cb ascending = col ascending
            const int col = m0 + wn * 64 + cb * 16 + lc;
            #pragma unroll
            for (int r2 = 0; r2 < 4; ++r2) {
                float v = acc[rb][cb][r2];
                int s = rb * 4 + r2;
                if (v > bv[s]) { bv[s] = v; bc[s] = col; }
            }
        }

    // reduce across the 16 lc lanes (xor<16 stays in the quad-group)
    #pragma unroll
    for (int off = 1; off < 16; off <<= 1) {
        #pragma unroll
        for (int s = 0; s < 16; ++s) {
            float ov = __shfl_xor(bv[s], off, 64);
            int   oi = __shfl_xor(bc[s], off, 64);
            if (ov > bv[s] || (ov == bv[s] && oi < bc[s])) { bv[s] = ov; bc[s] = oi; }
        }
    }

    // combine 6 column-chunk waves per row via LDS table [128][6].
    // wn ascending = col ascending: strict '>' keeps first-max semantics.
    float* v2s = (float*)(smem + 131072);
    int*   i2s = (int*)(smem + 131072 + 3072);

    if (lc == 0) {
        #pragma unroll
        for (int rb = 0; rb < 4; ++rb)
            #pragma unroll
            for (int r2 = 0; r2 < 4; ++r2) {
                int row = wm * 64 + rb * 16 + lq * 4 + r2;
                v2s[row * 6 + wn] = bv[rb * 4 + r2];
                i2s[row * 6 + wn] = bc[rb * 4 + r2];
            }
    }
    __syncthreads();
    if (t < 128) {
        float b = v2s[t * 6]; int bi = i2s[t * 6];
        #pragma unroll
        for (int q = 1; q < 6; ++q) {
            float v = v2s[t * 6 + q];
            if (v > b) { b = v; bi = i2s[t * 6 + q]; }
        }
        pmax[(size_t)tx * NP + n0 + t] = b;
        pidx[(size_t)tx * NP + n0 + t] = bi;
    }
}

// ---------------- Kernel 3: reduce 24 chunk partials -> nn_idx -------------
__global__ __launch_bounds__(256) void kred(
    const float* __restrict__ pmax, const int* __restrict__ pidx,
    int* __restrict__ nn)
{
    __shared__ float cv[4][64];
    __shared__ int   ci[4][64];

    const int t = threadIdx.x;
    const int n = blockIdx.x * 64 + (t & 63);
    const int p = t >> 6;

    float b = -INFINITY;
    int bi = 0x7fffffff;
    #pragma unroll
    for (int c = p * 6; c < p * 6 + 6; ++c) {
        float v = pmax[(size_t)c * NP + n];
        int  id = pidx[(size_t)c * NP + n];
        if (v > b || (v == b && id < bi)) { b = v; bi = id; }
    }
    cv[p][t & 63] = b;
    ci[p][t & 63] = bi;
    __syncthreads();
    if (t < 64) {
        b = cv[0][t]; bi = ci[0][t];
        #pragma unroll
        for (int q = 1; q < 4; ++q) {
            float v = cv[q][t]; int id = ci[q][t];
            if (v > b || (v == b && id < bi)) { b = v; bi = id; }
        }
        nn[blockIdx.x * 64 + t] = bi;
    }
}

// ---------------- Kernel 4: gather Y_sel + fused MSE loss ----------------
// y = (H + R) * 2^-8 (H/R same scale; error ~2^-22 relative).
__global__ __launch_bounds__(256) void kgather(
    const unsigned short* __restrict__ YH, const unsigned short* __restrict__ YR,
    const int* __restrict__ nn,
    const float* __restrict__ Xf, float* __restrict__ Ysel,
    float* __restrict__ lacc)
{
    __shared__ float tile[64][65];
    __shared__ int   idxs[64];
    __shared__ float wsum[4];

    const int n0 = blockIdx.x * 64;
    const int d0 = blockIdx.y * 64;
    const int tid = threadIdx.x;

    if (tid < 64) idxs[tid] = nn[n0 + tid];
    __syncthreads();

    const int c  = tid & 63;
    const int r0 = tid >> 6;

    #pragma unroll
    for (int s = 0; s < 16; ++s) {
        int r = s * 4 + r0;
        int d = d0 + c;
        size_t off = (size_t)(d >> 5) * KCH + (size_t)idxs[r] * 32 + (d & 31);
        tile[r][c] = (h2f(YH[off]) + h2f(YR[off])) * (1.0f / 256.0f);
    }
    __syncthreads();

    float lsum = 0.0f;
    #pragma unroll
    for (int s = 0; s < 16; ++s) {
        int a = s * 4 + r0;
        int d = d0 + a;
        int n = n0 + c;
        float y = tile[c][a];          // stride-65: conflict-free
        float x = Xf[(size_t)d * NP + n];
        float diff = x - y;
        lsum = fmaf(diff, diff, lsum);
        Ysel[(size_t)d * NP + n] = y;  // coalesced over n
    }

    #pragma unroll
    for (int off = 32; off >= 1; off >>= 1)
        lsum += __shfl_xor(lsum, off, 64);
    if ((tid & 63) == 0) wsum[tid >> 6] = lsum;
    __syncthreads();
    if (tid == 0)
        atomicAdd(lacc, wsum[0] + wsum[1] + wsum[2] + wsum[3]);
}

// ---------------- Kernel 5: finalize loss ----------------
__global__ void kfin(const float* __restrict__ lacc, float* __restrict__ out)
{
    out[0] = lacc[0] * (1.0f / (float)DN);
}

extern "C" void kernel_launch(void* const* d_in, const int* in_sizes, int n_in,
                              void* d_out, int out_size, void* d_ws, size_t ws_size,
                              hipStream_t stream)
{
    const float* X = (const float*)d_in[0];   // X_features [1,256,96,96]
    const float* Y = (const float*)d_in[1];   // Y_features [1,256,96,96]
    // d_in[2], d_in[3] (images) are dead code in the reference — unused.

    float* out = (float*)d_out;
    float* Ysel_out = out + 1;          // output 1: Y_sel [1,D,N]
    float* Xf_out   = out + 1 + DN;     // output 2: Xf   [1,D,N]  (exact fp32)

    // Workspace (~20 MB). XH|XR MUST be contiguous (ksim derives XR = XH+DN).
    unsigned short* XH = (unsigned short*)d_ws;   // DN halves each
    unsigned short* XR = XH + DN;
    unsigned short* YH = XR + DN;
    unsigned short* YR = YH + DN;
    float* pmax = (float*)(YR + DN);                 // NCH*NP
    int*   pidx = (int*)(pmax + (size_t)NCH * NP);   // NCH*NP
    int*   nn   = pidx + (size_t)NCH * NP;           // NP
    float* lacc = (float*)(nn + NP);                 // 1

    static bool attr_done = false;
    if (!attr_done) {
        hipFuncSetAttribute(reinterpret_cast<const void*>(ksim),
                            hipFuncAttributeMaxDynamicSharedMemorySize, 137216);
        attr_done = true;
    }

    hipLaunchKernelGGL(kprep, dim3(NP / 64, 2), dim3(256), 0, stream,
                       X, Y, Xf_out, XH, XR, YH, YR, lacc);
    hipLaunchKernelGGL(ksim, dim3(NCH, NST), dim3(768), 137216, stream,
                       XH, YH, YR, pmax, pidx);
    hipLaunchKernelGGL(kred, dim3(NP / 64), dim3(256), 0, stream,
                       pmax, pidx, nn);
    hipLaunchKernelGGL(kgather, dim3(NP / 64, DC / 64), dim3(256), 0, stream,
                       YH, YR, nn, Xf_out, Ysel_out, lacc);
    hipLaunchKernelGGL(kfin, dim3(1), dim3(1), 0, stream, lacc, out);
}

// Round 7
// 247.218 us; speedup vs baseline: 1.2508x; 1.0146x over previous
//
#include <hip/hip_runtime.h>
#include <math.h>

// Problem constants (B=1 fixed by reference)
#define NP 9216          // S*S spatial positions
#define DC 256           // channels
#define DN (DC * NP)
#define NTB 36           // 9216 / 256 tiles per dim
#define KCH (NP * 32)    // halves per k-chunk section of a plane

#define FEPS 2.220446049250313e-16f

typedef __attribute__((ext_vector_type(8))) _Float16 half8v;
typedef __attribute__((ext_vector_type(4))) float   float4v;

union HU { _Float16 h; unsigned short u; };
__device__ __forceinline__ unsigned short f2h(float f) { HU x; x.h = (_Float16)f; return x.u; }
__device__ __forceinline__ float h2f(unsigned short s) { HU x; x.u = s; return (float)x.h; }

// Plane layout (k-major): half index off(n,k) = (k>>5)*KCH + n*32 + (k&31)
// Split (same scale): s' = v*inv*2^8; H = fp16(s'), R = fp16(s' - H).
// sim*2^16 = Hx.Hy + Hx.Ry + Rx.Hy (Rx.Ry dropped, ~2^-22 rel).
//
// R7 model: R6 counters show B still issued 2x (wm waves load identical
// fragments): 96 KB/CU/kt > 23 B/cyc wall = 4170 cyc vs 2800 MFMA ->
// still byte-bound; prefetch rightly returned ~0. Fix: 256x256 tile with
// BOTH operands deduped through LDS. Issued 1.58 GB -> 678 MB; staged
// 64 KB/kt at 2780 cyc < MFMA 3725 cyc (4 w/SIMD) -> compute-bound.
// 16 waves, 128 KB LDS dbuf, 1-deep prefetch, __syncthreads drain (DMA
// has the whole MFMA phase to land). R6's verified involution swizzle.

// ---------------- Kernel 1: fused normalize + fp16 H/R split ----------------
__global__ __launch_bounds__(256) void kprep(
    const float* __restrict__ X, const float* __restrict__ Y,
    float* __restrict__ Xf_out,
    unsigned short* __restrict__ XH, unsigned short* __restrict__ XR,
    unsigned short* __restrict__ YH, unsigned short* __restrict__ YR,
    float* __restrict__ lacc)
{
    __shared__ float tile[64 * 257];   // (n, d) at n*257+d
    __shared__ float psum[4][64];
    __shared__ float invs[64];

    const int t = threadIdx.x;
    const bool isX = (blockIdx.y == 0);
    const float* src = isX ? X : Y;
    unsigned* hT = (unsigned*)(isX ? XH : YH);
    unsigned* rT = (unsigned*)(isX ? XR : YR);
    const int n0 = blockIdx.x * 64;

    if (blockIdx.x == 0 && blockIdx.y == 0 && t == 0) *lacc = 0.0f;

    const int lane = t & 63;
    const int w    = t >> 6;      // wave id -> owns d-range [w*64, w*64+64)

    #pragma unroll 8
    for (int i = 0; i < 64; ++i) {
        int d = w * 64 + i;
        tile[lane * 257 + d] = src[(size_t)d * NP + n0 + lane];
    }
    float s = 0.0f;
    #pragma unroll 8
    for (int i = 0; i < 64; ++i) {
        float v = tile[lane * 257 + w * 64 + i];
        s = fmaf(v, v, s);
    }
    psum[w][lane] = s;
    __syncthreads();
    if (t < 64) {
        float tot = psum[0][t] + psum[1][t] + psum[2][t] + psum[3][t];
        invs[t] = 1.0f / (sqrtf(tot) + FEPS);
    }
    __syncthreads();

    // plane writes, k-major layout; coalesced uints.
    for (int kt = 0; kt < 8; ++kt) {
        #pragma unroll
        for (int p = 0; p < 4; ++p) {
            int idx = p * 256 + t;
            int n = idx >> 4;          // 0..63
            int u = idx & 15;          // uint within chunk (2 halves)
            float inv = invs[n] * 256.0f;
            int d = kt * 32 + 2 * u;
            float s0 = tile[n * 257 + d] * inv;
            float s1 = tile[n * 257 + d + 1] * inv;
            unsigned short h0 = f2h(s0), h1 = f2h(s1);
            unsigned short r0 = f2h(s0 - h2f(h0));
            unsigned short r1 = f2h(s1 - h2f(h1));
            size_t uo = (size_t)kt * (NP * 16) + (size_t)(n0 + n) * 16 + u;
            hT[uo] = (unsigned)h0 | ((unsigned)h1 << 16);
            rT[uo] = (unsigned)r0 | ((unsigned)r1 << 16);
        }
    }

    // exact fp32 Xf output ([d][n], coalesced over n)
    if (isX) {
        const float inv = invs[lane];
        #pragma unroll 8
        for (int i = 0; i < 64; ++i) {
            int d = w * 64 + i;
            Xf_out[(size_t)d * NP + n0 + lane] = tile[lane * 257 + d] * inv;
        }
    }
}

// ---------------- Kernel 2: 256x256 both-in-LDS MFMA GEMM + argmax ---------
__device__ __forceinline__ void glds16(const char* g, char* l)
{
    __builtin_amdgcn_global_load_lds(
        (const __attribute__((address_space(1))) void*)g,
        (__attribute__((address_space(3))) void*)l, 16, 0, 0);
}

__global__ __launch_bounds__(1024, 1) void ksim(
    const unsigned short* __restrict__ XH,
    const unsigned short* __restrict__ YH,
    float* __restrict__ pmax, int* __restrict__ pidx)
{
    extern __shared__ char smem[];   // 2 x (A 32K | B 32K) = 128 KB

    const int t = threadIdx.x;
    const size_t PLB = 2 * (size_t)DN;            // H -> R plane byte offset
    const size_t KTB = 2 * (size_t)KCH;           // per-kt chunk byte stride

    // ---- XCD swizzle: 1296 blocks = 8 XCD x 162 (9 cols x 18 rows patch) --
    const int lid = blockIdx.y * NTB + blockIdx.x;
    const int xcd = lid & 7;
    const int r   = lid >> 3;                  // 0..161
    const int ti  = (xcd >> 2) * 18 + r / 9;   // row tile 0..35
    const int tj  = (xcd & 3) * 9 + r % 9;     // col tile 0..35
    const int n0  = ti * 256;                  // X rows
    const int m0  = tj * 256;                  // Y cols

    const int L = t & 63, wid = t >> 6;        // 16 waves: 4M x 4N
    const int wm = wid >> 2, wn = wid & 3;
    const int lc = L & 15,  lq = L >> 4;

    // staging: per-thread 16B seg; source inverse-swizzled (R6-verified
    // involution: XOR bits 4-5 of in-row offset with (row>>1)&3)
    const char* Ab = (const char*)XH + (size_t)n0 * 64;
    const char* Bb = (const char*)YH + (size_t)m0 * 64;
    const int dOf = t * 16;
    const int dSw = dOf ^ (((dOf >> 7) & 3) << 4);

    float4v acc[4][4];
    #pragma unroll
    for (int i = 0; i < 4; ++i)
        #pragma unroll
        for (int j = 0; j < 4; ++j)
            acc[i][j] = (float4v){0.f, 0.f, 0.f, 0.f};

    // ---- prologue: stage kt0 ----
    glds16(Ab + dSw,       smem + dOf);
    glds16(Ab + PLB + dSw, smem + 16384 + dOf);
    glds16(Bb + dSw,       smem + 32768 + dOf);
    glds16(Bb + PLB + dSw, smem + 49152 + dOf);
    __syncthreads();

    // swizzled fragment read offsets (row = strip + lc; (row>>1)&3 == (lc>>1)&3)
    const int xr  = (lq * 16) ^ (((lc >> 1) & 3) << 4);
    const int axr = (wm * 64 + lc) * 64 + xr;
    const int bxr = (wn * 64 + lc) * 64 + xr;

    #pragma unroll 1
    for (int kt = 0; kt < 8; ++kt) {
        const char* cur = smem + (kt & 1) * 65536;

        if (kt < 7) {   // stage kt+1 into the other buffer (in flight across MFMAs)
            char* nxt = smem + ((kt + 1) & 1) * 65536;
            const size_t kb = (size_t)(kt + 1) * KTB;
            glds16(Ab + kb + dSw,       nxt + dOf);
            glds16(Ab + PLB + kb + dSw, nxt + 16384 + dOf);
            glds16(Bb + kb + dSw,       nxt + 32768 + dOf);
            glds16(Bb + PLB + kb + dSw, nxt + 49152 + dOf);
        }

        // cb-pair MFMA sweep (B live set 16 VGPR, A transient 8)
        #pragma unroll
        for (int h = 0; h < 2; ++h) {
            half8v B0h = *(const half8v*)(cur + 32768 + bxr + (2 * h)     * 1024);
            half8v B1h = *(const half8v*)(cur + 32768 + bxr + (2 * h + 1) * 1024);
            half8v B0r = *(const half8v*)(cur + 49152 + bxr + (2 * h)     * 1024);
            half8v B1r = *(const half8v*)(cur + 49152 + bxr + (2 * h + 1) * 1024);
            #pragma unroll
            for (int rb = 0; rb < 4; ++rb) {
                half8v Ah = *(const half8v*)(cur +         axr + rb * 1024);
                half8v Ar = *(const half8v*)(cur + 16384 + axr + rb * 1024);
                float4v v0 = acc[rb][2 * h];
                float4v v1 = acc[rb][2 * h + 1];
                v0 = __builtin_amdgcn_mfma_f32_16x16x32_f16(Ah, B0h, v0, 0, 0, 0);
                v0 = __builtin_amdgcn_mfma_f32_16x16x32_f16(Ah, B0r, v0, 0, 0, 0);
                v0 = __builtin_amdgcn_mfma_f32_16x16x32_f16(Ar, B0h, v0, 0, 0, 0);
                v1 = __builtin_amdgcn_mfma_f32_16x16x32_f16(Ah, B1h, v1, 0, 0, 0);
                v1 = __builtin_amdgcn_mfma_f32_16x16x32_f16(Ah, B1r, v1, 0, 0, 0);
                v1 = __builtin_amdgcn_mfma_f32_16x16x32_f16(Ar, B1h, v1, 0, 0, 0);
                acc[rb][2 * h]     = v0;
                acc[rb][2 * h + 1] = v1;
            }
        }

        if (kt < 7) __syncthreads();   // drains next-tile DMA (had full MFMA phase)
    }

    // ---- epilogue: per-row argmax over this wave's 64 cols ----
    // C/D map: col=lane&15, row=lq*4+reg. Scale 2^16 is argmax-invariant.
    float bv[16]; int bc[16];
    #pragma unroll
    for (int s = 0; s < 16; ++s) { bv[s] = -INFINITY; bc[s] = 0; }

    #pragma unroll
    for (int rb = 0; rb < 4; ++rb)
        #pragma unroll
        for (int cb = 0; cb < 4; ++cb) {   // cb ascending = col ascending
            const int col = m0 + wn * 64 + cb * 16 + lc;
            #pragma unroll
            for (int r2 = 0; r2 < 4; ++r2) {
                float v = acc[rb][cb][r2];
                int s = rb * 4 + r2;
                if (v > bv[s]) { bv[s] = v; bc[s] = col; }
            }
        }

    // reduce across the 16 lc lanes (xor<16 stays in the quad-group)
    #pragma unroll
    for (int off = 1; off < 16; off <<= 1) {
        #pragma unroll
        for (int s = 0; s < 16; ++s) {
            float ov = __shfl_xor(bv[s], off, 64);
            int   oi = __shfl_xor(bc[s], off, 64);
            if (ov > bv[s] || (ov == bv[s] && oi < bc[s])) { bv[s] = ov; bc[s] = oi; }
        }
    }

    // combine 4 column waves per row via LDS table [256][4] (reuses buf0:
    // last read at kt6; every wave passed the kt6-end barrier).
    float* v2s = (float*)smem;
    int*   i2s = (int*)(smem + 4096);

    if (lc == 0) {
        #pragma unroll
        for (int rb = 0; rb < 4; ++rb)
            #pragma unroll
            for (int r2 = 0; r2 < 4; ++r2) {
                int row = wm * 64 + rb * 16 + lq * 4 + r2;
                v2s[row * 4 + wn] = bv[rb * 4 + r2];
                i2s[row * 4 + wn] = bc[rb * 4 + r2];
            }
    }
    __syncthreads();
    if (t < 256) {
        // wn ascending = col ascending: strict '>' keeps first-max semantics.
        float b = v2s[t * 4]; int bi = i2s[t * 4];
        #pragma unroll
        for (int q = 1; q < 4; ++q) {
            float v = v2s[t * 4 + q];
            if (v > b) { b = v; bi = i2s[t * 4 + q]; }
        }
        pmax[(size_t)tj * NP + n0 + t] = b;
        pidx[(size_t)tj * NP + n0 + t] = bi;
    }
}

// ---------------- Kernel 3: reduce 36 tile partials -> nn_idx -------------
__global__ __launch_bounds__(256) void kred(
    const float* __restrict__ pmax, const int* __restrict__ pidx,
    int* __restrict__ nn)
{
    __shared__ float cv[4][64];
    __shared__ int   ci[4][64];

    const int t = threadIdx.x;
    const int n = blockIdx.x * 64 + (t & 63);
    const int p = t >> 6;

    float b = -INFINITY;
    int bi = 0x7fffffff;
    #pragma unroll
    for (int c = p * 9; c < p * 9 + 9; ++c) {
        float v = pmax[(size_t)c * NP + n];
        int  id = pidx[(size_t)c * NP + n];
        if (v > b || (v == b && id < bi)) { b = v; bi = id; }
    }
    cv[p][t & 63] = b;
    ci[p][t & 63] = bi;
    __syncthreads();
    if (t < 64) {
        b = cv[0][t]; bi = ci[0][t];
        #pragma unroll
        for (int q = 1; q < 4; ++q) {
            float v = cv[q][t]; int id = ci[q][t];
            if (v > b || (v == b && id < bi)) { b = v; bi = id; }
        }
        nn[blockIdx.x * 64 + t] = bi;
    }
}

// ---------------- Kernel 4: gather Y_sel + fused MSE loss ----------------
// y = (H + R) * 2^-8 (H/R same scale; error ~2^-22 relative).
__global__ __launch_bounds__(256) void kgather(
    const unsigned short* __restrict__ YH, const unsigned short* __restrict__ YR,
    const int* __restrict__ nn,
    const float* __restrict__ Xf, float* __restrict__ Ysel,
    float* __restrict__ lacc)
{
    __shared__ float tile[64][65];
    __shared__ int   idxs[64];
    __shared__ float wsum[4];

    const int n0 = blockIdx.x * 64;
    const int d0 = blockIdx.y * 64;
    const int tid = threadIdx.x;

    if (tid < 64) idxs[tid] = nn[n0 + tid];
    __syncthreads();

    const int c  = tid & 63;
    const int r0 = tid >> 6;

    #pragma unroll
    for (int s = 0; s < 16; ++s) {
        int r = s * 4 + r0;
        int d = d0 + c;
        size_t off = (size_t)(d >> 5) * KCH + (size_t)idxs[r] * 32 + (d & 31);
        tile[r][c] = (h2f(YH[off]) + h2f(YR[off])) * (1.0f / 256.0f);
    }
    __syncthreads();

    float lsum = 0.0f;
    #pragma unroll
    for (int s = 0; s < 16; ++s) {
        int a = s * 4 + r0;
        int d = d0 + a;
        int n = n0 + c;
        float y = tile[c][a];          // stride-65: conflict-free
        float x = Xf[(size_t)d * NP + n];
        float diff = x - y;
        lsum = fmaf(diff, diff, lsum);
        Ysel[(size_t)d * NP + n] = y;  // coalesced over n
    }

    #pragma unroll
    for (int off = 32; off >= 1; off >>= 1)
        lsum += __shfl_xor(lsum, off, 64);
    if ((tid & 63) == 0) wsum[tid >> 6] = lsum;
    __syncthreads();
    if (tid == 0)
        atomicAdd(lacc, wsum[0] + wsum[1] + wsum[2] + wsum[3]);
}

// ---------------- Kernel 5: finalize loss ----------------
__global__ void kfin(const float* __restrict__ lacc, float* __restrict__ out)
{
    out[0] = lacc[0] * (1.0f / (float)DN);
}

extern "C" void kernel_launch(void* const* d_in, const int* in_sizes, int n_in,
                              void* d_out, int out_size, void* d_ws, size_t ws_size,
                              hipStream_t stream)
{
    const float* X = (const float*)d_in[0];   // X_features [1,256,96,96]
    const float* Y = (const float*)d_in[1];   // Y_features [1,256,96,96]
    // d_in[2], d_in[3] (images) are dead code in the reference — unused.

    float* out = (float*)d_out;
    float* Ysel_out = out + 1;          // output 1: Y_sel [1,D,N]
    float* Xf_out   = out + 1 + DN;     // output 2: Xf   [1,D,N]  (exact fp32)

    // Workspace (~22 MB). XH|XR and YH|YR MUST be contiguous pairs
    // (ksim derives R = H + 2*DN bytes).
    unsigned short* XH = (unsigned short*)d_ws;   // DN halves each
    unsigned short* XR = XH + DN;
    unsigned short* YH = XR + DN;
    unsigned short* YR = YH + DN;
    float* pmax = (float*)(YR + DN);                 // NTB*NP
    int*   pidx = (int*)(pmax + (size_t)NTB * NP);   // NTB*NP
    int*   nn   = pidx + (size_t)NTB * NP;           // NP
    float* lacc = (float*)(nn + NP);                 // 1

    static bool attr_done = false;
    if (!attr_done) {
        hipFuncSetAttribute(reinterpret_cast<const void*>(ksim),
                            hipFuncAttributeMaxDynamicSharedMemorySize, 131072);
        attr_done = true;
    }

    hipLaunchKernelGGL(kprep, dim3(NP / 64, 2), dim3(256), 0, stream,
                       X, Y, Xf_out, XH, XR, YH, YR, lacc);
    hipLaunchKernelGGL(ksim, dim3(NTB, NTB), dim3(1024), 131072, stream,
                       XH, YH, pmax, pidx);
    hipLaunchKernelGGL(kred, dim3(NP / 64), dim3(256), 0, stream,
                       pmax, pidx, nn);
    hipLaunchKernelGGL(kgather, dim3(NP / 64, DC / 64), dim3(256), 0, stream,
                       YH, YR, nn, Xf_out, Ysel_out, lacc);
    hipLaunchKernelGGL(kfin, dim3(1), dim3(1), 0, stream, lacc, out);
}